// Round 3
// baseline (70.148 us; speedup 1.0000x reference)
//
#include <hip/hip_runtime.h>
#include <math.h>

// Problem: x[N=16,T=128,V=64,F=16] fp32, a[F=16] fp32.
// score[n,i,j] = (1/T) * sum_t sum_f a[f]*|x[n,t,i,f]-x[n,t,j,f]|
// e = exp(relu(score)); out[n,i,j] = e[n,i,j] / sum_i e[n,i,j]   (column norm)
//
// FUSED single kernel, zero workspace. Round-3 change: round-2's inner loop
// issued 20 VMEM/t per wave, 16 of them wave-uniform B-row float4 loads
// (16B payload each, full VMEM latency chains). Now the block's entire
// B-panel (4 j x 128 t x 64B = 32 KB) is staged into LDS once by all 1024
// threads; the inner loop reads B via uniform-address ds_read_b128
// (broadcast, conflict-free, LDS pipe). VMEM per t drops 20 -> 4 (the
// per-lane A-stream, contiguous 4 KB/wave, L2/XCD-local since same-n blocks
// share an XCD: block id = n + 16*z  =>  id%8 = n%8).
// Structure: 256 blocks (1/CU), 16 waves (4/SIMD); wave w owns 8 t's,
// computes partials for all 4 block j's; 16 KB LDS combine; waves 0-3
// finalize the 4 columns (i lives in lanes -> shuffle-sum normalizer).

#define Nn 16
#define Tt 128
#define Vv 64
#define Ff 16
#define WAVES 16
#define TPW (Tt / WAVES)    // 8 t's per wave
#define JPB 4               // j's per block

__global__ __launch_bounds__(1024, 4) void gls_fused(const float* __restrict__ x,
                                                     const float* __restrict__ a,
                                                     float* __restrict__ out) {
    const int n   = blockIdx.x;
    const int z   = blockIdx.y;
    const int j0  = z * JPB;
    const int tid = threadIdx.x;
    const int i   = tid & 63;
    const int w   = __builtin_amdgcn_readfirstlane(tid >> 6);

    // x[n] base, in float4 units (V*F/4 = 256 float4 per t)
    const float4* xg = (const float4*)x + (size_t)n * Tt * (Vv * Ff / 4);

    // ---- stage B-panel: rows j0..j0+3 for ALL t  (32 KB = 2048 float4) ----
    __shared__ float4 bs[Tt * JPB * (Ff / 4)];   // [t][jj][q] linear
#pragma unroll
    for (int k = tid; k < Tt * JPB * (Ff / 4); k += 1024) {
        const int t   = k >> 4;        // /16
        const int rem = k & 15;        // jj*4 + q
        bs[k] = xg[t * 256 + j0 * 4 + rem];
    }

    float af[Ff];
#pragma unroll
    for (int f = 0; f < Ff; ++f) af[f] = a[f];   // uniform -> SGPRs

    __syncthreads();

    float acc[JPB] = {0.f, 0.f, 0.f, 0.f};

#pragma unroll 2
    for (int t = 0; t < TPW; ++t) {
        const int tg = w * TPW + t;                    // this wave's global t
        const float4* xt = xg + (size_t)tg * 256;
        // A-row for lane i: 4 x dwordx4, 64B/lane -> contiguous 4KB per wave
        const float4 A0 = xt[i * 4 + 0];
        const float4 A1 = xt[i * 4 + 1];
        const float4 A2 = xt[i * 4 + 2];
        const float4 A3 = xt[i * 4 + 3];
        const float4* bt = &bs[tg * 16];               // uniform -> LDS bcast
#pragma unroll
        for (int jj = 0; jj < JPB; ++jj) {
            const float4 B0 = bt[jj * 4 + 0];
            const float4 B1 = bt[jj * 4 + 1];
            const float4 B2 = bt[jj * 4 + 2];
            const float4 B3 = bt[jj * 4 + 3];
            float s = acc[jj];
            s = fmaf(fabsf(A0.x - B0.x), af[0],  s);
            s = fmaf(fabsf(A0.y - B0.y), af[1],  s);
            s = fmaf(fabsf(A0.z - B0.z), af[2],  s);
            s = fmaf(fabsf(A0.w - B0.w), af[3],  s);
            s = fmaf(fabsf(A1.x - B1.x), af[4],  s);
            s = fmaf(fabsf(A1.y - B1.y), af[5],  s);
            s = fmaf(fabsf(A1.z - B1.z), af[6],  s);
            s = fmaf(fabsf(A1.w - B1.w), af[7],  s);
            s = fmaf(fabsf(A2.x - B2.x), af[8],  s);
            s = fmaf(fabsf(A2.y - B2.y), af[9],  s);
            s = fmaf(fabsf(A2.z - B2.z), af[10], s);
            s = fmaf(fabsf(A2.w - B2.w), af[11], s);
            s = fmaf(fabsf(A3.x - B3.x), af[12], s);
            s = fmaf(fabsf(A3.y - B3.y), af[13], s);
            s = fmaf(fabsf(A3.z - B3.z), af[14], s);
            s = fmaf(fabsf(A3.w - B3.w), af[15], s);
            acc[jj] = s;
        }
    }

    // ---- combine the 16 T-slices (16 KB LDS) ----
    __shared__ float part[WAVES][JPB][Vv];
#pragma unroll
    for (int jj = 0; jj < JPB; ++jj)
        part[w][jj][i] = acc[jj];                 // lane-contiguous, conflict-free
    __syncthreads();

    if (w < JPB) {
        // wave w finalizes column j = j0 + w; lane = row index i
        float s = 0.f;
#pragma unroll
        for (int p = 0; p < WAVES; ++p)
            s += part[p][w][i];
        const float e = expf(fmaxf(s * (1.0f / (float)Tt), 0.0f));
        float tsum = e;
#pragma unroll
        for (int m = 1; m < 64; m <<= 1) tsum += __shfl_xor(tsum, m, 64);

        out[((size_t)n * Vv + i) * Vv + (j0 + w)] = e / tsum;  // tiny scatter (256 KB total)
    }
}

extern "C" void kernel_launch(void* const* d_in, const int* in_sizes, int n_in,
                              void* d_out, int out_size, void* d_ws, size_t ws_size,
                              hipStream_t stream) {
    const float* x = (const float*)d_in[0];   // [16,128,64,16]
    const float* a = (const float*)d_in[1];   // [16,1]
    float* out = (float*)d_out;               // [16,64,64]
    (void)d_ws; (void)ws_size;                // workspace intentionally unused

    dim3 g(Nn, Vv / JPB);                     // (16, 16) = 256 blocks, 1/CU
    gls_fused<<<g, 1024, 0, stream>>>(x, a, out);
}

// Round 4
// 67.677 us; speedup vs baseline: 1.0365x; 1.0365x over previous
//
#include <hip/hip_runtime.h>
#include <math.h>

// Problem: x[N=16,T=128,V=64,F=16] fp32, a[F=16] fp32.
// score[n,i,j] = (1/T) * sum_t sum_f a[f]*|x[n,t,i,f]-x[n,t,j,f]|
// e = exp(relu(score)); out[n,i,j] = e[n,i,j] / sum_i e[n,i,j]   (column norm)
//
// FUSED single kernel, zero workspace — round-2 configuration (best: 67.3us),
// reverting round-3's LDS B-panel staging which regressed (B-row broadcast
// loads were already cheap L1 hits; staging added prologue + sync + LDS-pipe
// pressure for nothing).
//  - 256 blocks (1/CU), 1024 threads = 16 waves (4/SIMD) for latency hiding.
//  - Block owns (n, 4 j's, full T): column-norm (sum over i) is block-local
//    since i lives in the 64 lanes -> no workspace, no second kernel.
//  - Wave w owns T/16 = 8 timesteps; A-rows per-lane dwordx4 x4 (contiguous
//    4KB/wave, L1/L2-served; same-n blocks share an XCD: id%8 = n%8);
//    B-rows wave-uniform -> broadcast loads of warm lines.
//  - 16 KB LDS combine over T-slices; waves 0-3 finalize the 4 columns with
//    a 64-lane shuffle-sum normalizer.

#define Nn 16
#define Tt 128
#define Vv 64
#define Ff 16
#define WAVES 16
#define TPW (Tt / WAVES)    // 8 t's per wave
#define JPB 4               // j's per block

__global__ __launch_bounds__(1024, 4) void gls_fused(const float* __restrict__ x,
                                                     const float* __restrict__ a,
                                                     float* __restrict__ out) {
    const int n   = blockIdx.x;
    const int z   = blockIdx.y;
    const int j0  = z * JPB;
    const int tid = threadIdx.x;
    const int i   = tid & 63;
    const int w   = __builtin_amdgcn_readfirstlane(tid >> 6);

    float af[Ff];
#pragma unroll
    for (int f = 0; f < Ff; ++f) af[f] = a[f];   // uniform -> SGPRs

    float acc[JPB] = {0.f, 0.f, 0.f, 0.f};

    // base of this wave's T-slice, in float4 units (V*F/4 = 256 float4 per t)
    const float4* xb = (const float4*)x + (size_t)(n * Tt + w * TPW) * (Vv * Ff / 4);

#pragma unroll 2
    for (int t = 0; t < TPW; ++t) {
        const float4* xt = xb + (size_t)t * (Vv * Ff / 4);
        // A-row for lane i: 4 x dwordx4, 64B/lane -> contiguous 4KB per wave
        const float4 A0 = xt[i * 4 + 0];
        const float4 A1 = xt[i * 4 + 1];
        const float4 A2 = xt[i * 4 + 2];
        const float4 A3 = xt[i * 4 + 3];
#pragma unroll
        for (int jj = 0; jj < JPB; ++jj) {
            const float4* xj = xt + (j0 + jj) * 4;   // wave-uniform -> broadcast
            const float4 B0 = xj[0];
            const float4 B1 = xj[1];
            const float4 B2 = xj[2];
            const float4 B3 = xj[3];
            float s = acc[jj];
            s = fmaf(fabsf(A0.x - B0.x), af[0],  s);
            s = fmaf(fabsf(A0.y - B0.y), af[1],  s);
            s = fmaf(fabsf(A0.z - B0.z), af[2],  s);
            s = fmaf(fabsf(A0.w - B0.w), af[3],  s);
            s = fmaf(fabsf(A1.x - B1.x), af[4],  s);
            s = fmaf(fabsf(A1.y - B1.y), af[5],  s);
            s = fmaf(fabsf(A1.z - B1.z), af[6],  s);
            s = fmaf(fabsf(A1.w - B1.w), af[7],  s);
            s = fmaf(fabsf(A2.x - B2.x), af[8],  s);
            s = fmaf(fabsf(A2.y - B2.y), af[9],  s);
            s = fmaf(fabsf(A2.z - B2.z), af[10], s);
            s = fmaf(fabsf(A2.w - B2.w), af[11], s);
            s = fmaf(fabsf(A3.x - B3.x), af[12], s);
            s = fmaf(fabsf(A3.y - B3.y), af[13], s);
            s = fmaf(fabsf(A3.z - B3.z), af[14], s);
            s = fmaf(fabsf(A3.w - B3.w), af[15], s);
            acc[jj] = s;
        }
    }

    // ---- combine the 16 T-slices (16 KB LDS) ----
    __shared__ float part[WAVES][JPB][Vv];
#pragma unroll
    for (int jj = 0; jj < JPB; ++jj)
        part[w][jj][i] = acc[jj];                 // lane-contiguous, conflict-free
    __syncthreads();

    if (w < JPB) {
        // wave w finalizes column j = j0 + w; lane = row index i
        float s = 0.f;
#pragma unroll
        for (int p = 0; p < WAVES; ++p)
            s += part[p][w][i];
        const float e = expf(fmaxf(s * (1.0f / (float)Tt), 0.0f));
        float tsum = e;
#pragma unroll
        for (int m = 1; m < 64; m <<= 1) tsum += __shfl_xor(tsum, m, 64);

        out[((size_t)n * Vv + i) * Vv + (j0 + w)] = e / tsum;  // tiny scatter (256 KB total)
    }
}

extern "C" void kernel_launch(void* const* d_in, const int* in_sizes, int n_in,
                              void* d_out, int out_size, void* d_ws, size_t ws_size,
                              hipStream_t stream) {
    const float* x = (const float*)d_in[0];   // [16,128,64,16]
    const float* a = (const float*)d_in[1];   // [16,1]
    float* out = (float*)d_out;               // [16,64,64]
    (void)d_ws; (void)ws_size;                // workspace intentionally unused

    dim3 g(Nn, Vv / JPB);                     // (16, 16) = 256 blocks, 1/CU
    gls_fused<<<g, 1024, 0, stream>>>(x, a, out);
}